// Round 4
// baseline (2725.250 us; speedup 1.0000x reference)
//
#include <hip/hip_runtime.h>
#include <hip/hip_bf16.h>
#include <stdint.h>

// MoE: B=2,S=4096 -> T=8192 tokens, D=1024, E=8, H=2736 (pad->2816), TOPK=2
#define T_TOK 8192
#define DIM   1024
#define NEXP  8
#define HDIM  2736
#define HPAD  2816   // 22 * 128, zero-padded rows/cols are inert

typedef __attribute__((ext_vector_type(8))) short          short8;   // 8 bf16 (4 VGPRs) MFMA operand
typedef __attribute__((ext_vector_type(8))) unsigned short ushort8;
typedef __attribute__((ext_vector_type(4))) float          f32x4;

__device__ __forceinline__ unsigned short f2bf(float f) {
  unsigned u = __float_as_uint(f);
  u = (u + 0x7FFFu + ((u >> 16) & 1u)) >> 16;   // round-to-nearest-even
  return (unsigned short)u;
}

__device__ __forceinline__ void gld_lds16(const ushort* g, ushort* l) {
  // async global->LDS, 16B/lane; LDS dest must be wave-uniform base (lane*16 added by HW)
  __builtin_amdgcn_global_load_lds((const __attribute__((address_space(1))) uint32_t*)g,
                                   (__attribute__((address_space(3))) uint32_t*)l,
                                   16, 0, 0);
}

// Stage a 128x64 bf16 tile (row stride ldK elements) into linear LDS [128][64].
// 1024 16B-chunks = 256 threads x 4. Chunk c -> row=c>>3, col8=c&7; LDS linear at c*16B.
__device__ __forceinline__ void stage64(const ushort* __restrict__ src, int ldK,
                                        ushort* lds, int tid) {
#pragma unroll
  for (int i = 0; i < 4; ++i) {
    int c = i * 256 + tid;
    int row = c >> 3, col8 = c & 7;
    gld_lds16(src + (size_t)row * ldK + col8 * 8,
              lds + (size_t)(i * 256 + (tid & 192)) * 8);  // wave-uniform base chunk
  }
}

// ---------------- conversion kernels ----------------
__global__ void cvt_x_kernel(const float* __restrict__ in, ushort* __restrict__ out, int n8) {
  int i = blockIdx.x * 256 + threadIdx.x;
  if (i >= n8) return;
  const float4* p = (const float4*)in + (size_t)i * 2;
  float4 a = p[0], b = p[1];
  ushort8 v;
  v[0]=f2bf(a.x); v[1]=f2bf(a.y); v[2]=f2bf(a.z); v[3]=f2bf(a.w);
  v[4]=f2bf(b.x); v[5]=f2bf(b.y); v[6]=f2bf(b.z); v[7]=f2bf(b.w);
  ((ushort8*)out)[i] = v;
}

// in [E,H,D] fp32 -> out [E,Hp,D] bf16, rows >= H zeroed. D=1024 (D/8=128 pow2).
__global__ void cvt_pad_rows_kernel(const float* __restrict__ in, ushort* __restrict__ out, int n8) {
  int i = blockIdx.x * 256 + threadIdx.x;
  if (i >= n8) return;
  int col = i & 127;          // D/8 = 128
  int rowAll = i >> 7;        // [0, E*Hp)
  int e = rowAll / HPAD;
  int r = rowAll - e * HPAD;
  ushort8 v = (ushort8)0;
  if (r < HDIM) {
    const float4* p = (const float4*)(in + ((size_t)(e * HDIM + r) * DIM + col * 8));
    float4 a = p[0], b = p[1];
    v[0]=f2bf(a.x); v[1]=f2bf(a.y); v[2]=f2bf(a.z); v[3]=f2bf(a.w);
    v[4]=f2bf(b.x); v[5]=f2bf(b.y); v[6]=f2bf(b.z); v[7]=f2bf(b.w);
  }
  ((ushort8*)out)[i] = v;
}

// in [E,D,H] fp32 -> out [E,D,Hp] bf16, inner cols >= H zeroed. H divisible by 8.
__global__ void cvt_pad_inner_kernel(const float* __restrict__ in, ushort* __restrict__ out, int n8) {
  int i = blockIdx.x * 256 + threadIdx.x;
  if (i >= n8) return;
  int h8 = HPAD / 8;          // 352
  int c = i % h8;
  int rowAll = i / h8;        // [0, E*D)
  int h0 = c * 8;
  ushort8 v = (ushort8)0;
  if (h0 < HDIM) {
    const float4* p = (const float4*)(in + (size_t)rowAll * HDIM + h0);
    float4 a = p[0], b = p[1];
    v[0]=f2bf(a.x); v[1]=f2bf(a.y); v[2]=f2bf(a.z); v[3]=f2bf(a.w);
    v[4]=f2bf(b.x); v[5]=f2bf(b.y); v[6]=f2bf(b.z); v[7]=f2bf(b.w);
  }
  ((ushort8*)out)[i] = v;
}

// ---------------- router: one wave per token ----------------
__global__ void router_kernel(const float* __restrict__ X, const float* __restrict__ GW,
                              float* __restrict__ comb) {
  int wave = threadIdx.x >> 6, lane = threadIdx.x & 63;
  int t = blockIdx.x * 4 + wave;
  if (t >= T_TOK) return;
  float acc[NEXP];
#pragma unroll
  for (int e = 0; e < NEXP; ++e) acc[e] = 0.f;
  const float4* xv = (const float4*)(X + (size_t)t * DIM);
#pragma unroll
  for (int it = 0; it < DIM / 4 / 64; ++it) {   // 4 iterations
    int c = it * 64 + lane;
    float4 xx = xv[c];
#pragma unroll
    for (int e = 0; e < NEXP; ++e) {
      float4 w = ((const float4*)(GW + (size_t)e * DIM))[c];
      acc[e] += xx.x * w.x + xx.y * w.y + xx.z * w.z + xx.w * w.w;
    }
  }
#pragma unroll
  for (int e = 0; e < NEXP; ++e)
#pragma unroll
    for (int off = 32; off > 0; off >>= 1)
      acc[e] += __shfl_down(acc[e], off, 64);
  if (lane == 0) {
    float m = acc[0];
#pragma unroll
    for (int e = 1; e < NEXP; ++e) m = fmaxf(m, acc[e]);
    float p[NEXP], s = 0.f;
#pragma unroll
    for (int e = 0; e < NEXP; ++e) { p[e] = expf(acc[e] - m); s += p[e]; }
#pragma unroll
    for (int e = 0; e < NEXP; ++e) p[e] /= s;
    int i0 = 0;
#pragma unroll
    for (int e = 1; e < NEXP; ++e) if (p[e] > p[i0]) i0 = e;   // ties -> lowest idx, matches top_k
    int i1 = (i0 == 0) ? 1 : 0;
#pragma unroll
    for (int e = 0; e < NEXP; ++e) if (e != i0 && p[e] > p[i1]) i1 = e;
    float denom = p[i0] + p[i1] + 1e-8f;
#pragma unroll
    for (int e = 0; e < NEXP; ++e) comb[(size_t)t * NEXP + e] = 0.f;
    comb[(size_t)t * NEXP + i0] = p[i0] / denom;
    comb[(size_t)t * NEXP + i1] = p[i1] / denom;
  }
}

// ---------------- GEMM1 fused: h = silu(X@Wg^T) * (X@W1^T), one expert ----------------
// 128x128 tile, BK=64, 4 waves (2x2), each wave 64x64 = 4x4 fragments of 16x16x32.
__global__ __launch_bounds__(256) void gemm1_kernel(
    const ushort* __restrict__ X,     // [T, D] bf16
    const ushort* __restrict__ Wgp,   // [HPAD, D] bf16 (expert slice)
    const ushort* __restrict__ Wup,   // [HPAD, D]
    ushort* __restrict__ Hout)        // [T, HPAD] bf16
{
  __shared__ ushort As[128 * 64];
  __shared__ ushort Bg[128 * 64];
  __shared__ ushort Bu[128 * 64];
  int tid = threadIdx.x;
  int lane = tid & 63, wave = tid >> 6;
  int wr = wave >> 1, wc = wave & 1;
  int lhi = lane >> 4, llo = lane & 15;
  int brow = blockIdx.x * 128, bcol = blockIdx.y * 128;

  f32x4 accg[4][4], accu[4][4];
#pragma unroll
  for (int m = 0; m < 4; ++m)
#pragma unroll
    for (int n = 0; n < 4; ++n) { accg[m][n] = (f32x4){0,0,0,0}; accu[m][n] = (f32x4){0,0,0,0}; }

  const ushort* Ab  = X   + (size_t)brow * DIM;
  const ushort* Bgb = Wgp + (size_t)bcol * DIM;
  const ushort* Bub = Wup + (size_t)bcol * DIM;

  for (int ko = 0; ko < DIM; ko += 64) {
    stage64(Ab  + ko, DIM, As, tid);
    stage64(Bgb + ko, DIM, Bg, tid);
    stage64(Bub + ko, DIM, Bu, tid);
    __syncthreads();           // compiler emits vmcnt(0) drain before barrier
    const short8* As8 = (const short8*)As;
    const short8* Bg8 = (const short8*)Bg;
    const short8* Bu8 = (const short8*)Bu;
#pragma unroll
    for (int kk = 0; kk < 2; ++kk) {
      short8 a[4], bg[4], bu[4];
#pragma unroll
      for (int m = 0; m < 4; ++m)
        a[m] = As8[(wr * 64 + m * 16 + llo) * 8 + kk * 4 + lhi];
#pragma unroll
      for (int n = 0; n < 4; ++n) {
        bg[n] = Bg8[(wc * 64 + n * 16 + llo) * 8 + kk * 4 + lhi];
        bu[n] = Bu8[(wc * 64 + n * 16 + llo) * 8 + kk * 4 + lhi];
      }
#pragma unroll
      for (int m = 0; m < 4; ++m)
#pragma unroll
        for (int n = 0; n < 4; ++n) {
          accg[m][n] = __builtin_amdgcn_mfma_f32_16x16x32_bf16(a[m], bg[n], accg[m][n], 0, 0, 0);
          accu[m][n] = __builtin_amdgcn_mfma_f32_16x16x32_bf16(a[m], bu[n], accu[m][n], 0, 0, 0);
        }
    }
    __syncthreads();
  }
  // epilogue: silu(g)*u -> bf16.  C/D layout: col=lane&15, row=(lane>>4)*4+j  [m89]
#pragma unroll
  for (int m = 0; m < 4; ++m)
#pragma unroll
    for (int n = 0; n < 4; ++n)
#pragma unroll
      for (int j = 0; j < 4; ++j) {
        int row = brow + wr * 64 + m * 16 + lhi * 4 + j;
        int col = bcol + wc * 64 + n * 16 + llo;
        float g = accg[m][n][j];
        float u = accu[m][n][j];
        float h = g / (1.f + __expf(-g)) * u;
        Hout[(size_t)row * HPAD + col] = f2bf(h);
      }
}

// ---------------- GEMM2: Out += combine[:,e] * (Hb @ W2^T), one expert ----------------
__global__ __launch_bounds__(256) void gemm2_kernel(
    const ushort* __restrict__ Hin,   // [T, HPAD] bf16
    const ushort* __restrict__ W2p,   // [DIM, HPAD] bf16 (expert slice)
    const float* __restrict__ comb,   // [T, NEXP]
    float* __restrict__ Out,          // [T, DIM] fp32, pre-zeroed
    int e)
{
  __shared__ ushort As[128 * 64];
  __shared__ ushort Bs[128 * 64];
  int tid = threadIdx.x;
  int lane = tid & 63, wave = tid >> 6;
  int wr = wave >> 1, wc = wave & 1;
  int lhi = lane >> 4, llo = lane & 15;
  int brow = blockIdx.x * 128, bcol = blockIdx.y * 128;

  f32x4 acc[4][4];
#pragma unroll
  for (int m = 0; m < 4; ++m)
#pragma unroll
    for (int n = 0; n < 4; ++n) acc[m][n] = (f32x4){0,0,0,0};

  const ushort* Ab = Hin + (size_t)brow * HPAD;
  const ushort* Bb = W2p + (size_t)bcol * HPAD;

  for (int ko = 0; ko < HPAD; ko += 64) {
    stage64(Ab + ko, HPAD, As, tid);
    stage64(Bb + ko, HPAD, Bs, tid);
    __syncthreads();
    const short8* As8 = (const short8*)As;
    const short8* Bs8 = (const short8*)Bs;
#pragma unroll
    for (int kk = 0; kk < 2; ++kk) {
      short8 a[4], b[4];
#pragma unroll
      for (int m = 0; m < 4; ++m)
        a[m] = As8[(wr * 64 + m * 16 + llo) * 8 + kk * 4 + lhi];
#pragma unroll
      for (int n = 0; n < 4; ++n)
        b[n] = Bs8[(wc * 64 + n * 16 + llo) * 8 + kk * 4 + lhi];
#pragma unroll
      for (int m = 0; m < 4; ++m)
#pragma unroll
        for (int n = 0; n < 4; ++n)
          acc[m][n] = __builtin_amdgcn_mfma_f32_16x16x32_bf16(a[m], b[n], acc[m][n], 0, 0, 0);
    }
    __syncthreads();
  }
#pragma unroll
  for (int m = 0; m < 4; ++m)
#pragma unroll
    for (int j = 0; j < 4; ++j) {
      int row = brow + wr * 64 + m * 16 + lhi * 4 + j;
      float cw = comb[(size_t)row * NEXP + e];
#pragma unroll
      for (int n = 0; n < 4; ++n) {
        int col = bcol + wc * 64 + n * 16 + llo;
        Out[(size_t)row * DIM + col] += cw * acc[m][n][j];
      }
    }
}

extern "C" void kernel_launch(void* const* d_in, const int* in_sizes, int n_in,
                              void* d_out, int out_size, void* d_ws, size_t ws_size,
                              hipStream_t stream) {
  const float* x  = (const float*)d_in[0];   // [T, D]
  const float* gw = (const float*)d_in[1];   // [E, D]
  const float* Wg = (const float*)d_in[2];   // [E, H, D]
  const float* W1 = (const float*)d_in[3];   // [E, H, D]
  const float* W2 = (const float*)d_in[4];   // [E, D, H]
  float* out = (float*)d_out;                // [T, D] fp32

  // workspace layout (total ~202 MB)
  char* p = (char*)d_ws;
  ushort* xb  = (ushort*)p; p += (size_t)T_TOK * DIM * 2;
  ushort* Wgb = (ushort*)p; p += (size_t)NEXP * HPAD * DIM * 2;
  ushort* W1b = (ushort*)p; p += (size_t)NEXP * HPAD * DIM * 2;
  ushort* W2b = (ushort*)p; p += (size_t)NEXP * DIM * HPAD * 2;
  ushort* hb  = (ushort*)p; p += (size_t)T_TOK * HPAD * 2;
  float*  comb = (float*)p; p += (size_t)T_TOK * NEXP * 4;

  hipMemsetAsync(d_out, 0, (size_t)T_TOK * DIM * 4, stream);

  { int n8 = T_TOK * DIM / 8;
    cvt_x_kernel<<<n8 / 256, 256, 0, stream>>>(x, xb, n8); }
  { int n8 = NEXP * HPAD * DIM / 8;
    cvt_pad_rows_kernel<<<n8 / 256, 256, 0, stream>>>(Wg, Wgb, n8);
    cvt_pad_rows_kernel<<<n8 / 256, 256, 0, stream>>>(W1, W1b, n8);
    cvt_pad_inner_kernel<<<n8 / 256, 256, 0, stream>>>(W2, W2b, n8); }

  router_kernel<<<T_TOK / 4, 256, 0, stream>>>(x, gw, comb);

  for (int e = 0; e < NEXP; ++e) {
    gemm1_kernel<<<dim3(T_TOK / 128, HPAD / 128), 256, 0, stream>>>(
        xb, Wgb + (size_t)e * HPAD * DIM, W1b + (size_t)e * HPAD * DIM, hb);
    gemm2_kernel<<<dim3(T_TOK / 128, DIM / 128), 256, 0, stream>>>(
        hb, W2b + (size_t)e * DIM * HPAD, comb, out, e);
  }
}

// Round 6
// 2052.058 us; speedup vs baseline: 1.3281x; 1.3281x over previous
//
#include <hip/hip_runtime.h>
#include <hip/hip_bf16.h>
#include <stdint.h>

// MoE: B=2,S=4096 -> T=8192 tokens, D=1024, E=8, H=2736 (pad->2816), TOPK=2
#define T_TOK 8192
#define DIM   1024
#define NEXP  8
#define HDIM  2736
#define HPAD  2816     // 22 * 128, zero-padded rows/cols are inert
#define CAP   16384    // worst-case tokens per expert (2*T slots total)
#define HB_ROWS 17408  // 16384 + 8*128 padding, compact h capacity

typedef __attribute__((ext_vector_type(8))) short          short8;   // 8 bf16 (4 VGPRs) MFMA operand
typedef __attribute__((ext_vector_type(8))) unsigned short ushort8;
typedef __attribute__((ext_vector_type(4))) float          f32x4;

__device__ __forceinline__ unsigned short f2bf(float f) {
  unsigned u = __float_as_uint(f);
  u = (u + 0x7FFFu + ((u >> 16) & 1u)) >> 16;   // round-to-nearest-even
  return (unsigned short)u;
}

__device__ __forceinline__ void gld_lds16(const ushort* g, ushort* l) {
  // async global->LDS, 16B/lane; LDS dest must be wave-uniform base (lane*16 added by HW)
  __builtin_amdgcn_global_load_lds((const __attribute__((address_space(1))) uint32_t*)g,
                                   (__attribute__((address_space(3))) uint32_t*)l,
                                   16, 0, 0);
}

// Stage a 128x64 bf16 tile (row stride ldK elements) into linear LDS [128][64].
// 1024 16B-chunks = 256 threads x 4. Chunk c -> row=c>>3, col8=c&7; LDS linear at c*16B.
__device__ __forceinline__ void stage64(const ushort* __restrict__ src, int ldK,
                                        ushort* lds, int tid) {
#pragma unroll
  for (int i = 0; i < 4; ++i) {
    int c = i * 256 + tid;
    int row = c >> 3, col8 = c & 7;
    gld_lds16(src + (size_t)row * ldK + col8 * 8,
              lds + (size_t)(i * 256 + (tid & 192)) * 8);  // wave-uniform base chunk
  }
}

// ---------------- conversion kernels ----------------
__global__ void cvt_x_kernel(const float* __restrict__ in, ushort* __restrict__ out, int n8) {
  int i = blockIdx.x * 256 + threadIdx.x;
  if (i >= n8) return;
  const float4* p = (const float4*)in + (size_t)i * 2;
  float4 a = p[0], b = p[1];
  ushort8 v;
  v[0]=f2bf(a.x); v[1]=f2bf(a.y); v[2]=f2bf(a.z); v[3]=f2bf(a.w);
  v[4]=f2bf(b.x); v[5]=f2bf(b.y); v[6]=f2bf(b.z); v[7]=f2bf(b.w);
  ((ushort8*)out)[i] = v;
}

// in [E,H,D] fp32 -> out [E,Hp,D] bf16, rows >= H zeroed. D=1024 (D/8=128 pow2).
__global__ void cvt_pad_rows_kernel(const float* __restrict__ in, ushort* __restrict__ out, int n8) {
  int i = blockIdx.x * 256 + threadIdx.x;
  if (i >= n8) return;
  int col = i & 127;          // D/8 = 128
  int rowAll = i >> 7;        // [0, E*Hp)
  int e = rowAll / HPAD;
  int r = rowAll - e * HPAD;
  ushort8 v = (ushort8)0;
  if (r < HDIM) {
    const float4* p = (const float4*)(in + ((size_t)(e * HDIM + r) * DIM + col * 8));
    float4 a = p[0], b = p[1];
    v[0]=f2bf(a.x); v[1]=f2bf(a.y); v[2]=f2bf(a.z); v[3]=f2bf(a.w);
    v[4]=f2bf(b.x); v[5]=f2bf(b.y); v[6]=f2bf(b.z); v[7]=f2bf(b.w);
  }
  ((ushort8*)out)[i] = v;
}

// in [E,D,H] fp32 -> out [E,D,Hp] bf16, inner cols >= H zeroed. H divisible by 8.
__global__ void cvt_pad_inner_kernel(const float* __restrict__ in, ushort* __restrict__ out, int n8) {
  int i = blockIdx.x * 256 + threadIdx.x;
  if (i >= n8) return;
  int h8 = HPAD / 8;          // 352
  int c = i % h8;
  int rowAll = i / h8;        // [0, E*D)
  int h0 = c * 8;
  ushort8 v = (ushort8)0;
  if (h0 < HDIM) {
    const float4* p = (const float4*)(in + (size_t)rowAll * HDIM + h0);
    float4 a = p[0], b = p[1];
    v[0]=f2bf(a.x); v[1]=f2bf(a.y); v[2]=f2bf(a.z); v[3]=f2bf(a.w);
    v[4]=f2bf(b.x); v[5]=f2bf(b.y); v[6]=f2bf(b.z); v[7]=f2bf(b.w);
  }
  ((ushort8*)out)[i] = v;
}

// ---------------- router: one wave per token; appends to per-expert lists ----------------
__global__ void router_kernel(const float* __restrict__ X, const float* __restrict__ GW,
                              int* __restrict__ cnt, int* __restrict__ tok,
                              float* __restrict__ wt) {
  int wave = threadIdx.x >> 6, lane = threadIdx.x & 63;
  int t = blockIdx.x * 4 + wave;
  if (t >= T_TOK) return;
  float acc[NEXP];
#pragma unroll
  for (int e = 0; e < NEXP; ++e) acc[e] = 0.f;
  const float4* xv = (const float4*)(X + (size_t)t * DIM);
#pragma unroll
  for (int it = 0; it < DIM / 4 / 64; ++it) {   // 4 iterations
    int c = it * 64 + lane;
    float4 xx = xv[c];
#pragma unroll
    for (int e = 0; e < NEXP; ++e) {
      float4 w = ((const float4*)(GW + (size_t)e * DIM))[c];
      acc[e] += xx.x * w.x + xx.y * w.y + xx.z * w.z + xx.w * w.w;
    }
  }
#pragma unroll
  for (int e = 0; e < NEXP; ++e)
#pragma unroll
    for (int off = 32; off > 0; off >>= 1)
      acc[e] += __shfl_down(acc[e], off, 64);
  if (lane == 0) {
    float m = acc[0];
#pragma unroll
    for (int e = 1; e < NEXP; ++e) m = fmaxf(m, acc[e]);
    float p[NEXP], s = 0.f;
#pragma unroll
    for (int e = 0; e < NEXP; ++e) { p[e] = expf(acc[e] - m); s += p[e]; }
#pragma unroll
    for (int e = 0; e < NEXP; ++e) p[e] /= s;
    int i0 = 0;
#pragma unroll
    for (int e = 1; e < NEXP; ++e) if (p[e] > p[i0]) i0 = e;   // ties -> lowest idx, matches top_k
    int i1 = (i0 == 0) ? 1 : 0;
#pragma unroll
    for (int e = 0; e < NEXP; ++e) if (e != i0 && p[e] > p[i1]) i1 = e;
    float denom = p[i0] + p[i1] + 1e-8f;
    int pos0 = atomicAdd(&cnt[i0], 1);
    tok[i0 * CAP + pos0] = t;
    wt[i0 * CAP + pos0] = p[i0] / denom;
    int pos1 = atomicAdd(&cnt[i1], 1);
    tok[i1 * CAP + pos1] = t;
    wt[i1 * CAP + pos1] = p[i1] / denom;
  }
}

// 128-aligned segment offsets for compact h
__global__ void offsets_kernel(const int* __restrict__ cnt, int* __restrict__ off) {
  if (threadIdx.x == 0 && blockIdx.x == 0) {
    int o = 0;
#pragma unroll
    for (int e = 0; e < NEXP; ++e) { off[e] = o; o += (cnt[e] + 127) & ~127; }
    off[NEXP] = o;
  }
}

// ---------------- GEMM1 fused sparse: h = silu(Xg@Wg^T) * (Xg@W1^T), one expert ----------------
// A rows gathered from xb via token list during global_load_lds staging (per-lane global addr).
__global__ __launch_bounds__(256) void gemm1_kernel(
    const ushort* __restrict__ X,     // [T, D] bf16
    const ushort* __restrict__ Wgp,   // [HPAD, D] bf16 (expert slice)
    const ushort* __restrict__ Wup,   // [HPAD, D]
    ushort* __restrict__ Hout,        // [HB_ROWS, HPAD] compact
    const int* __restrict__ tokl,     // expert's token list
    const int* __restrict__ cntp,     // &cnt[e]
    const int* __restrict__ offp)     // &off[e]
{
  int cnt = *cntp;
  int brow = blockIdx.x * 128;
  int cntpad = (cnt + 127) & ~127;
  if (brow >= cntpad) return;       // early-exit capacity blocks
  int hoff = *offp;

  __shared__ ushort As[128 * 64];
  __shared__ ushort Bg[128 * 64];
  __shared__ ushort Bu[128 * 64];
  int tid = threadIdx.x;
  int lane = tid & 63, wave = tid >> 6;
  int wr = wave >> 1, wc = wave & 1;
  int lhi = lane >> 4, llo = lane & 15;
  int bcol = blockIdx.y * 128;

  // per-thread gathered A source pointers (4 staged rows per thread)
  int baserow = tid >> 3, col8 = tid & 7;
  const ushort* asrc[4];
#pragma unroll
  for (int i = 0; i < 4; ++i) {
    int p = brow + baserow + 32 * i;
    int t = (p < cnt) ? tokl[p] : 0;   // padded rows: read token 0, result discarded
    asrc[i] = X + (size_t)t * DIM + col8 * 8;
  }

  f32x4 accg[4][4], accu[4][4];
#pragma unroll
  for (int m = 0; m < 4; ++m)
#pragma unroll
    for (int n = 0; n < 4; ++n) { accg[m][n] = (f32x4){0,0,0,0}; accu[m][n] = (f32x4){0,0,0,0}; }

  const ushort* Bgb = Wgp + (size_t)bcol * DIM;
  const ushort* Bub = Wup + (size_t)bcol * DIM;

  for (int ko = 0; ko < DIM; ko += 64) {
#pragma unroll
    for (int i = 0; i < 4; ++i)   // gathered A stage
      gld_lds16(asrc[i] + ko, As + (size_t)(i * 256 + (tid & 192)) * 8);
    stage64(Bgb + ko, DIM, Bg, tid);
    stage64(Bub + ko, DIM, Bu, tid);
    __syncthreads();
    const short8* As8 = (const short8*)As;
    const short8* Bg8 = (const short8*)Bg;
    const short8* Bu8 = (const short8*)Bu;
#pragma unroll
    for (int kk = 0; kk < 2; ++kk) {
      short8 a[4], bg[4], bu[4];
#pragma unroll
      for (int m = 0; m < 4; ++m)
        a[m] = As8[(wr * 64 + m * 16 + llo) * 8 + kk * 4 + lhi];
#pragma unroll
      for (int n = 0; n < 4; ++n) {
        bg[n] = Bg8[(wc * 64 + n * 16 + llo) * 8 + kk * 4 + lhi];
        bu[n] = Bu8[(wc * 64 + n * 16 + llo) * 8 + kk * 4 + lhi];
      }
#pragma unroll
      for (int m = 0; m < 4; ++m)
#pragma unroll
        for (int n = 0; n < 4; ++n) {
          accg[m][n] = __builtin_amdgcn_mfma_f32_16x16x32_bf16(a[m], bg[n], accg[m][n], 0, 0, 0);
          accu[m][n] = __builtin_amdgcn_mfma_f32_16x16x32_bf16(a[m], bu[n], accu[m][n], 0, 0, 0);
        }
    }
    __syncthreads();
  }
  // epilogue: silu(g)*u -> bf16 into compact h.  C/D layout: col=lane&15, row=(lane>>4)*4+j  [m89]
#pragma unroll
  for (int m = 0; m < 4; ++m)
#pragma unroll
    for (int n = 0; n < 4; ++n)
#pragma unroll
      for (int j = 0; j < 4; ++j) {
        int row = hoff + brow + wr * 64 + m * 16 + lhi * 4 + j;
        int col = bcol + wc * 64 + n * 16 + llo;
        float g = accg[m][n][j];
        float u = accu[m][n][j];
        float h = g / (1.f + __expf(-g)) * u;
        Hout[(size_t)row * HPAD + col] = f2bf(h);
      }
}

// ---------------- GEMM2 sparse: Out[tok[p]] += wt[p] * (h_seg @ W2^T), one expert ----------------
// No race: tokens unique within an expert; experts launched sequentially (plain RMW,
// expert order 0..7 matches reference summation order).
__global__ __launch_bounds__(256) void gemm2_kernel(
    const ushort* __restrict__ Hin,   // [HB_ROWS, HPAD] compact
    const ushort* __restrict__ W2p,   // [DIM, HPAD] bf16 (expert slice)
    const int* __restrict__ tokl,
    const float* __restrict__ wtl,
    float* __restrict__ Out,          // [T, DIM] fp32, pre-zeroed
    const int* __restrict__ cntp,
    const int* __restrict__ offp)
{
  int cnt = *cntp;
  int brow = blockIdx.x * 128;
  int cntpad = (cnt + 127) & ~127;
  if (brow >= cntpad) return;
  int hoff = *offp;

  __shared__ ushort As[128 * 64];
  __shared__ ushort Bs[128 * 64];
  int tid = threadIdx.x;
  int lane = tid & 63, wave = tid >> 6;
  int wr = wave >> 1, wc = wave & 1;
  int lhi = lane >> 4, llo = lane & 15;
  int bcol = blockIdx.y * 128;

  f32x4 acc[4][4];
#pragma unroll
  for (int m = 0; m < 4; ++m)
#pragma unroll
    for (int n = 0; n < 4; ++n) acc[m][n] = (f32x4){0,0,0,0};

  const ushort* Ab = Hin + (size_t)(hoff + brow) * HPAD;
  const ushort* Bb = W2p + (size_t)bcol * HPAD;

  for (int ko = 0; ko < HPAD; ko += 64) {
    stage64(Ab + ko, HPAD, As, tid);
    stage64(Bb + ko, HPAD, Bs, tid);
    __syncthreads();
    const short8* As8 = (const short8*)As;
    const short8* Bs8 = (const short8*)Bs;
#pragma unroll
    for (int kk = 0; kk < 2; ++kk) {
      short8 a[4], b[4];
#pragma unroll
      for (int m = 0; m < 4; ++m)
        a[m] = As8[(wr * 64 + m * 16 + llo) * 8 + kk * 4 + lhi];
#pragma unroll
      for (int n = 0; n < 4; ++n)
        b[n] = Bs8[(wc * 64 + n * 16 + llo) * 8 + kk * 4 + lhi];
#pragma unroll
      for (int m = 0; m < 4; ++m)
#pragma unroll
        for (int n = 0; n < 4; ++n)
          acc[m][n] = __builtin_amdgcn_mfma_f32_16x16x32_bf16(a[m], b[n], acc[m][n], 0, 0, 0);
    }
    __syncthreads();
  }
#pragma unroll
  for (int m = 0; m < 4; ++m)
#pragma unroll
    for (int j = 0; j < 4; ++j) {
      int p = brow + wr * 64 + m * 16 + lhi * 4 + j;   // position in expert's list
      if (p < cnt) {
        int t = tokl[p];
        float cw = wtl[p];
#pragma unroll
        for (int n = 0; n < 4; ++n) {
          int col = bcol + wc * 64 + n * 16 + llo;
          Out[(size_t)t * DIM + col] += cw * acc[m][n][j];
        }
      }
    }
}

extern "C" void kernel_launch(void* const* d_in, const int* in_sizes, int n_in,
                              void* d_out, int out_size, void* d_ws, size_t ws_size,
                              hipStream_t stream) {
  const float* x  = (const float*)d_in[0];   // [T, D]
  const float* gw = (const float*)d_in[1];   // [E, D]
  const float* Wg = (const float*)d_in[2];   // [E, H, D]
  const float* W1 = (const float*)d_in[3];   // [E, H, D]
  const float* W2 = (const float*)d_in[4];   // [E, D, H]
  float* out = (float*)d_out;                // [T, D] fp32

  // workspace layout (~255 MB)
  char* p = (char*)d_ws;
  ushort* xb  = (ushort*)p; p += (size_t)T_TOK * DIM * 2;
  ushort* Wgb = (ushort*)p; p += (size_t)NEXP * HPAD * DIM * 2;
  ushort* W1b = (ushort*)p; p += (size_t)NEXP * HPAD * DIM * 2;
  ushort* W2b = (ushort*)p; p += (size_t)NEXP * DIM * HPAD * 2;
  ushort* hb  = (ushort*)p; p += (size_t)HB_ROWS * HPAD * 2;
  int*    tok = (int*)p;    p += (size_t)NEXP * CAP * 4;
  float*  wt  = (float*)p;  p += (size_t)NEXP * CAP * 4;
  int*    cnt = (int*)p;    p += NEXP * 4;
  int*    off = (int*)p;    p += (NEXP + 1) * 4;

  hipMemsetAsync(d_out, 0, (size_t)T_TOK * DIM * 4, stream);
  hipMemsetAsync(cnt, 0, NEXP * 4, stream);

  { int n8 = T_TOK * DIM / 8;
    cvt_x_kernel<<<n8 / 256, 256, 0, stream>>>(x, xb, n8); }
  { int n8 = NEXP * HPAD * DIM / 8;
    cvt_pad_rows_kernel<<<n8 / 256, 256, 0, stream>>>(Wg, Wgb, n8);
    cvt_pad_rows_kernel<<<n8 / 256, 256, 0, stream>>>(W1, W1b, n8);
    cvt_pad_inner_kernel<<<n8 / 256, 256, 0, stream>>>(W2, W2b, n8); }

  router_kernel<<<T_TOK / 4, 256, 0, stream>>>(x, gw, cnt, tok, wt);
  offsets_kernel<<<1, 64, 0, stream>>>(cnt, off);

  for (int e = 0; e < NEXP; ++e) {
    gemm1_kernel<<<dim3(CAP / 128, HPAD / 128), 256, 0, stream>>>(
        xb, Wgb + (size_t)e * HPAD * DIM, W1b + (size_t)e * HPAD * DIM, hb,
        tok + (size_t)e * CAP, cnt + e, off + e);
    gemm2_kernel<<<dim3(CAP / 128, DIM / 128), 256, 0, stream>>>(
        hb, W2b + (size_t)e * DIM * HPAD, tok + (size_t)e * CAP, wt + (size_t)e * CAP,
        out, cnt + e, off + e);
  }
}

// Round 10
// 1436.124 us; speedup vs baseline: 1.8976x; 1.4289x over previous
//
#include <hip/hip_runtime.h>
#include <hip/hip_bf16.h>
#include <stdint.h>

// MoE: B=2,S=4096 -> T=8192 tokens, D=1024, E=8, H=2736 (pad->2816), TOPK=2
#define T_TOK 8192
#define DIM   1024
#define NEXP  8
#define HDIM  2736
#define HPAD  2816     // 22 * 128, zero-padded rows/cols are inert
#define CAP   16384    // worst-case tokens per expert
#define HB_ROWS 17408  // 16384 + 8*128 padding, compact h capacity

typedef __attribute__((ext_vector_type(8))) short          short8;   // 8 bf16 (4 VGPRs) MFMA operand
typedef __attribute__((ext_vector_type(8))) unsigned short ushort8;
typedef __attribute__((ext_vector_type(4))) float          f32x4;

__device__ __forceinline__ unsigned short f2bf(float f) {
  unsigned u = __float_as_uint(f);
  u = (u + 0x7FFFu + ((u >> 16) & 1u)) >> 16;   // round-to-nearest-even
  return (unsigned short)u;
}

__device__ __forceinline__ void gld_lds16(const ushort* g, ushort* l) {
  // async global->LDS, 16B/lane; LDS dest must be wave-uniform base (lane*16 added by HW)
  __builtin_amdgcn_global_load_lds((const __attribute__((address_space(1))) uint32_t*)g,
                                   (__attribute__((address_space(3))) uint32_t*)l,
                                   16, 0, 0);
}

// Stage a 128x64 bf16 tile (row stride ldK elements) into linear LDS [128][64].
__device__ __forceinline__ void stage64(const ushort* __restrict__ src, int ldK,
                                        ushort* lds, int tid) {
#pragma unroll
  for (int i = 0; i < 4; ++i) {
    int c = i * 256 + tid;
    int row = c >> 3, col8 = c & 7;
    gld_lds16(src + (size_t)row * ldK + col8 * 8,
              lds + (size_t)(i * 256 + (tid & 192)) * 8);  // wave-uniform base chunk
  }
}

// ---------------- conversion kernels ----------------
__global__ void cvt_x_kernel(const float* __restrict__ in, ushort* __restrict__ out, int n8) {
  int i = blockIdx.x * 256 + threadIdx.x;
  if (i >= n8) return;
  const float4* p = (const float4*)in + (size_t)i * 2;
  float4 a = p[0], b = p[1];
  ushort8 v;
  v[0]=f2bf(a.x); v[1]=f2bf(a.y); v[2]=f2bf(a.z); v[3]=f2bf(a.w);
  v[4]=f2bf(b.x); v[5]=f2bf(b.y); v[6]=f2bf(b.z); v[7]=f2bf(b.w);
  ((ushort8*)out)[i] = v;
}

// in [E,H,D] fp32 -> out [E,Hp,D] bf16, rows >= H zeroed. D=1024 (D/8=128 pow2).
__global__ void cvt_pad_rows_kernel(const float* __restrict__ in, ushort* __restrict__ out, int n8) {
  int i = blockIdx.x * 256 + threadIdx.x;
  if (i >= n8) return;
  int col = i & 127;          // D/8 = 128
  int rowAll = i >> 7;        // [0, E*Hp)
  int e = rowAll / HPAD;
  int r = rowAll - e * HPAD;
  ushort8 v = (ushort8)0;
  if (r < HDIM) {
    const float4* p = (const float4*)(in + ((size_t)(e * HDIM + r) * DIM + col * 8));
    float4 a = p[0], b = p[1];
    v[0]=f2bf(a.x); v[1]=f2bf(a.y); v[2]=f2bf(a.z); v[3]=f2bf(a.w);
    v[4]=f2bf(b.x); v[5]=f2bf(b.y); v[6]=f2bf(b.z); v[7]=f2bf(b.w);
  }
  ((ushort8*)out)[i] = v;
}

// in [E,D,H] fp32 -> out [E,D,Hp] bf16, inner cols >= H zeroed.
__global__ void cvt_pad_inner_kernel(const float* __restrict__ in, ushort* __restrict__ out, int n8) {
  int i = blockIdx.x * 256 + threadIdx.x;
  if (i >= n8) return;
  int h8 = HPAD / 8;          // 352
  int c = i % h8;
  int rowAll = i / h8;        // [0, E*D)
  int h0 = c * 8;
  ushort8 v = (ushort8)0;
  if (h0 < HDIM) {
    const float4* p = (const float4*)(in + (size_t)rowAll * HDIM + h0);
    float4 a = p[0], b = p[1];
    v[0]=f2bf(a.x); v[1]=f2bf(a.y); v[2]=f2bf(a.z); v[3]=f2bf(a.w);
    v[4]=f2bf(b.x); v[5]=f2bf(b.y); v[6]=f2bf(b.z); v[7]=f2bf(b.w);
  }
  ((ushort8*)out)[i] = v;
}

// ---------------- topk: one wave per token, NO atomics ----------------
__global__ void topk_kernel(const float* __restrict__ X, const float* __restrict__ GW,
                            int* __restrict__ sel0, int* __restrict__ sel1,
                            float* __restrict__ w0, float* __restrict__ w1) {
  int wave = threadIdx.x >> 6, lane = threadIdx.x & 63;
  int t = blockIdx.x * 4 + wave;
  if (t >= T_TOK) return;
  float acc[NEXP];
#pragma unroll
  for (int e = 0; e < NEXP; ++e) acc[e] = 0.f;
  const float4* xv = (const float4*)(X + (size_t)t * DIM);
#pragma unroll
  for (int it = 0; it < DIM / 4 / 64; ++it) {
    int c = it * 64 + lane;
    float4 xx = xv[c];
#pragma unroll
    for (int e = 0; e < NEXP; ++e) {
      float4 w = ((const float4*)(GW + (size_t)e * DIM))[c];
      acc[e] += xx.x * w.x + xx.y * w.y + xx.z * w.z + xx.w * w.w;
    }
  }
#pragma unroll
  for (int e = 0; e < NEXP; ++e)
#pragma unroll
    for (int off = 32; off > 0; off >>= 1)
      acc[e] += __shfl_down(acc[e], off, 64);
  if (lane == 0) {
    float m = acc[0];
#pragma unroll
    for (int e = 1; e < NEXP; ++e) m = fmaxf(m, acc[e]);
    float p[NEXP], s = 0.f;
#pragma unroll
    for (int e = 0; e < NEXP; ++e) { p[e] = expf(acc[e] - m); s += p[e]; }
#pragma unroll
    for (int e = 0; e < NEXP; ++e) p[e] /= s;
    int i0 = 0;
#pragma unroll
    for (int e = 1; e < NEXP; ++e) if (p[e] > p[i0]) i0 = e;   // ties -> lowest idx, matches top_k
    int i1 = (i0 == 0) ? 1 : 0;
#pragma unroll
    for (int e = 0; e < NEXP; ++e) if (e != i0 && p[e] > p[i1]) i1 = e;
    float denom = p[i0] + p[i1] + 1e-8f;
    sel0[t] = i0; sel1[t] = i1;
    w0[t] = p[i0] / denom;
    w1[t] = p[i1] / denom;
  }
}

// ---------------- build per-expert token lists: 1 block/expert, ballot scan, no atomics ----------------
__global__ __launch_bounds__(1024) void build_lists_kernel(
    const int* __restrict__ sel0, const int* __restrict__ sel1,
    int* __restrict__ tok, int* __restrict__ rnk0, int* __restrict__ rnk1,
    int* __restrict__ cnt) {
  int e = blockIdx.x;
  int tid = threadIdx.x;
  int lane = tid & 63, wv = tid >> 6;   // 16 waves
  __shared__ int wsum[16], wbase[16], chunktot;
  int base = 0;
  for (int t0 = 0; t0 < T_TOK; t0 += 1024) {
    int t = t0 + tid;
    int s0 = sel0[t], s1 = sel1[t];
    bool isf = (s0 == e);
    bool hit = isf || (s1 == e);
    unsigned long long b = __ballot(hit);
    int rank = __popcll(b & ((1ULL << lane) - 1ULL));
    if (lane == 0) wsum[wv] = __popcll(b);
    __syncthreads();
    if (tid == 0) {
      int s = 0;
#pragma unroll
      for (int w = 0; w < 16; ++w) { wbase[w] = s; s += wsum[w]; }
      chunktot = s;
    }
    __syncthreads();
    if (hit) {
      int pos = base + wbase[wv] + rank;
      tok[e * CAP + pos] = t;
      if (isf) rnk0[t] = pos; else rnk1[t] = pos;
    }
    base += chunktot;
    __syncthreads();   // protect wsum/wbase/chunktot before next chunk overwrites
  }
  if (tid == 0) cnt[e] = base;
}

// 128-aligned segment offsets for compact h / yc
__global__ void offsets_kernel(const int* __restrict__ cnt, int* __restrict__ off) {
  if (threadIdx.x == 0 && blockIdx.x == 0) {
    int o = 0;
#pragma unroll
    for (int e = 0; e < NEXP; ++e) { off[e] = o; o += (cnt[e] + 127) & ~127; }
    off[NEXP] = o;
  }
}

// ---------------- GEMM1 fused sparse, all experts (z = expert) ----------------
__global__ __launch_bounds__(256) void gemm1_all_kernel(
    const ushort* __restrict__ X,     // [T, D] bf16
    const ushort* __restrict__ Wgb,   // [E, HPAD, D]
    const ushort* __restrict__ Wub,   // [E, HPAD, D]
    ushort* __restrict__ Hout,        // [HB_ROWS, HPAD] compact
    const int* __restrict__ tokall,   // [E, CAP]
    const int* __restrict__ cntv, const int* __restrict__ offv) {
  int e = blockIdx.z;
  int cnt = cntv[e];
  int brow = blockIdx.x * 128;
  int cntpad = (cnt + 127) & ~127;
  if (brow >= cntpad) return;       // early-exit capacity blocks
  int hoff = offv[e];
  const int* tokl = tokall + (size_t)e * CAP;

  __shared__ ushort As[128 * 64];
  __shared__ ushort Bg[128 * 64];
  __shared__ ushort Bu[128 * 64];
  int tid = threadIdx.x;
  int lane = tid & 63, wave = tid >> 6;
  int wr = wave >> 1, wc = wave & 1;
  int lhi = lane >> 4, llo = lane & 15;
  int bcol = blockIdx.y * 128;

  // per-thread gathered A source pointers (4 staged rows per thread)
  int baserow = tid >> 3, col8 = tid & 7;
  const ushort* asrc[4];
#pragma unroll
  for (int i = 0; i < 4; ++i) {
    int p = brow + baserow + 32 * i;
    int t = (p < cnt) ? tokl[p] : 0;   // padded rows: read token 0, result discarded
    asrc[i] = X + (size_t)t * DIM + col8 * 8;
  }

  f32x4 accg[4][4], accu[4][4];
#pragma unroll
  for (int m = 0; m < 4; ++m)
#pragma unroll
    for (int n = 0; n < 4; ++n) { accg[m][n] = (f32x4){0,0,0,0}; accu[m][n] = (f32x4){0,0,0,0}; }

  const ushort* Bgb2 = Wgb + (size_t)e * HPAD * DIM + (size_t)bcol * DIM;
  const ushort* Bub2 = Wub + (size_t)e * HPAD * DIM + (size_t)bcol * DIM;

  for (int ko = 0; ko < DIM; ko += 64) {
#pragma unroll
    for (int i = 0; i < 4; ++i)   // gathered A stage
      gld_lds16(asrc[i] + ko, As + (size_t)(i * 256 + (tid & 192)) * 8);
    stage64(Bgb2 + ko, DIM, Bg, tid);
    stage64(Bub2 + ko, DIM, Bu, tid);
    __syncthreads();
    const short8* As8 = (const short8*)As;
    const short8* Bg8 = (const short8*)Bg;
    const short8* Bu8 = (const short8*)Bu;
#pragma unroll
    for (int kk = 0; kk < 2; ++kk) {
      short8 a[4], bg[4], bu[4];
#pragma unroll
      for (int m = 0; m < 4; ++m)
        a[m] = As8[(wr * 64 + m * 16 + llo) * 8 + kk * 4 + lhi];
#pragma unroll
      for (int n = 0; n < 4; ++n) {
        bg[n] = Bg8[(wc * 64 + n * 16 + llo) * 8 + kk * 4 + lhi];
        bu[n] = Bu8[(wc * 64 + n * 16 + llo) * 8 + kk * 4 + lhi];
      }
#pragma unroll
      for (int m = 0; m < 4; ++m)
#pragma unroll
        for (int n = 0; n < 4; ++n) {
          accg[m][n] = __builtin_amdgcn_mfma_f32_16x16x32_bf16(a[m], bg[n], accg[m][n], 0, 0, 0);
          accu[m][n] = __builtin_amdgcn_mfma_f32_16x16x32_bf16(a[m], bu[n], accu[m][n], 0, 0, 0);
        }
    }
    __syncthreads();
  }
  // epilogue: silu(g)*u -> bf16 into compact h.  C/D layout: col=lane&15, row=(lane>>4)*4+j  [m89]
#pragma unroll
  for (int m = 0; m < 4; ++m)
#pragma unroll
    for (int n = 0; n < 4; ++n)
#pragma unroll
      for (int j = 0; j < 4; ++j) {
        int row = hoff + brow + wr * 64 + m * 16 + lhi * 4 + j;
        int col = bcol + wc * 64 + n * 16 + llo;
        float g = accg[m][n][j];
        float u = accu[m][n][j];
        float h = g / (1.f + __expf(-g)) * u;
        Hout[(size_t)row * HPAD + col] = f2bf(h);
      }
}

// ---------------- GEMM2 all experts: yc = h_seg @ W2^T (compact rows, plain stores) ----------------
__global__ __launch_bounds__(256) void gemm2_all_kernel(
    const ushort* __restrict__ Hin,   // [HB_ROWS, HPAD] compact
    const ushort* __restrict__ W2b,   // [E, DIM, HPAD]
    float* __restrict__ Yc,           // [HB_ROWS, DIM] fp32 compact
    const int* __restrict__ cntv, const int* __restrict__ offv) {
  int e = blockIdx.z;
  int cnt = cntv[e];
  int brow = blockIdx.x * 128;
  int cntpad = (cnt + 127) & ~127;
  if (brow >= cntpad) return;
  int hoff = offv[e];

  __shared__ ushort As[128 * 64];
  __shared__ ushort Bs[128 * 64];
  int tid = threadIdx.x;
  int lane = tid & 63, wave = tid >> 6;
  int wr = wave >> 1, wc = wave & 1;
  int lhi = lane >> 4, llo = lane & 15;
  int bcol = blockIdx.y * 128;

  f32x4 acc[4][4];
#pragma unroll
  for (int m = 0; m < 4; ++m)
#pragma unroll
    for (int n = 0; n < 4; ++n) acc[m][n] = (f32x4){0,0,0,0};

  const ushort* Ab = Hin + (size_t)(hoff + brow) * HPAD;
  const ushort* Bb = W2b + (size_t)e * DIM * HPAD + (size_t)bcol * HPAD;

  for (int ko = 0; ko < HPAD; ko += 64) {
    stage64(Ab + ko, HPAD, As, tid);
    stage64(Bb + ko, HPAD, Bs, tid);
    __syncthreads();
    const short8* As8 = (const short8*)As;
    const short8* Bs8 = (const short8*)Bs;
#pragma unroll
    for (int kk = 0; kk < 2; ++kk) {
      short8 a[4], b[4];
#pragma unroll
      for (int m = 0; m < 4; ++m)
        a[m] = As8[(wr * 64 + m * 16 + llo) * 8 + kk * 4 + lhi];
#pragma unroll
      for (int n = 0; n < 4; ++n)
        b[n] = Bs8[(wc * 64 + n * 16 + llo) * 8 + kk * 4 + lhi];
#pragma unroll
      for (int m = 0; m < 4; ++m)
#pragma unroll
        for (int n = 0; n < 4; ++n)
          acc[m][n] = __builtin_amdgcn_mfma_f32_16x16x32_bf16(a[m], b[n], acc[m][n], 0, 0, 0);
    }
    __syncthreads();
  }
#pragma unroll
  for (int m = 0; m < 4; ++m)
#pragma unroll
    for (int j = 0; j < 4; ++j) {
      int row = hoff + brow + wr * 64 + m * 16 + lhi * 4 + j;
#pragma unroll
      for (int n = 0; n < 4; ++n) {
        int col = bcol + wc * 64 + n * 16 + llo;
        Yc[(size_t)row * DIM + col] = acc[m][n][j];
      }
    }
}

// ---------------- combine: out[t] = w0*yc[r0] + w1*yc[r1]; 1 block per token ----------------
__global__ __launch_bounds__(256) void combine_kernel(
    const float* __restrict__ Yc,
    const int* __restrict__ sel0, const int* __restrict__ sel1,
    const float* __restrict__ w0, const float* __restrict__ w1,
    const int* __restrict__ rnk0, const int* __restrict__ rnk1,
    const int* __restrict__ offv, float* __restrict__ out) {
  int t = blockIdx.x;
  int c = threadIdx.x;           // DIM/4 = 256 float4 per row
  int r0 = offv[sel0[t]] + rnk0[t];
  int r1 = offv[sel1[t]] + rnk1[t];
  float a = w0[t], b = w1[t];
  float4 y0 = ((const float4*)(Yc + (size_t)r0 * DIM))[c];
  float4 y1 = ((const float4*)(Yc + (size_t)r1 * DIM))[c];
  float4 o;
  o.x = a * y0.x + b * y1.x;
  o.y = a * y0.y + b * y1.y;
  o.z = a * y0.z + b * y1.z;
  o.w = a * y0.w + b * y1.w;
  ((float4*)(out + (size_t)t * DIM))[c] = o;
}

extern "C" void kernel_launch(void* const* d_in, const int* in_sizes, int n_in,
                              void* d_out, int out_size, void* d_ws, size_t ws_size,
                              hipStream_t stream) {
  const float* x  = (const float*)d_in[0];   // [T, D]
  const float* gw = (const float*)d_in[1];   // [E, D]
  const float* Wg = (const float*)d_in[2];   // [E, H, D]
  const float* W1 = (const float*)d_in[3];   // [E, H, D]
  const float* W2 = (const float*)d_in[4];   // [E, D, H]
  float* out = (float*)d_out;                // [T, D] fp32

  // workspace layout (~255 MB). yc (71.3 MB fp32) aliases Wgb+W1b (92.3 MB),
  // both dead after gemm1_all completes (same-stream ordering).
  char* p = (char*)d_ws;
  ushort* xb  = (ushort*)p; p += (size_t)T_TOK * DIM * 2;
  ushort* Wgb = (ushort*)p; p += (size_t)NEXP * HPAD * DIM * 2;
  ushort* W1b = (ushort*)p; p += (size_t)NEXP * HPAD * DIM * 2;
  ushort* W2b = (ushort*)p; p += (size_t)NEXP * DIM * HPAD * 2;
  ushort* hb  = (ushort*)p; p += (size_t)HB_ROWS * HPAD * 2;
  int*    tok = (int*)p;    p += (size_t)NEXP * CAP * 4;
  int*   sel0 = (int*)p;    p += T_TOK * 4;
  int*   sel1 = (int*)p;    p += T_TOK * 4;
  float*   w0 = (float*)p;  p += T_TOK * 4;
  float*   w1 = (float*)p;  p += T_TOK * 4;
  int*   rnk0 = (int*)p;    p += T_TOK * 4;
  int*   rnk1 = (int*)p;    p += T_TOK * 4;
  int*    cnt = (int*)p;    p += NEXP * 4;
  int*    off = (int*)p;    p += (NEXP + 1) * 4;
  float*  yc  = (float*)Wgb;   // alias

  { int n8 = T_TOK * DIM / 8;
    cvt_x_kernel<<<n8 / 256, 256, 0, stream>>>(x, xb, n8); }
  { int n8 = NEXP * HPAD * DIM / 8;
    cvt_pad_rows_kernel<<<n8 / 256, 256, 0, stream>>>(Wg, Wgb, n8);
    cvt_pad_rows_kernel<<<n8 / 256, 256, 0, stream>>>(W1, W1b, n8);
    cvt_pad_inner_kernel<<<n8 / 256, 256, 0, stream>>>(W2, W2b, n8); }

  topk_kernel<<<T_TOK / 4, 256, 0, stream>>>(x, gw, sel0, sel1, w0, w1);
  build_lists_kernel<<<NEXP, 1024, 0, stream>>>(sel0, sel1, tok, rnk0, rnk1, cnt);
  offsets_kernel<<<1, 64, 0, stream>>>(cnt, off);

  gemm1_all_kernel<<<dim3(CAP / 128, HPAD / 128, NEXP), 256, 0, stream>>>(
      xb, Wgb, W1b, hb, tok, cnt, off);
  gemm2_all_kernel<<<dim3(CAP / 128, DIM / 128, NEXP), 256, 0, stream>>>(
      hb, W2b, yc, cnt, off);
  combine_kernel<<<T_TOK, 256, 0, stream>>>(yc, sel0, sel1, w0, w1, rnk0, rnk1, off, out);
}

// Round 11
// 944.998 us; speedup vs baseline: 2.8839x; 1.5197x over previous
//
#include <hip/hip_runtime.h>
#include <hip/hip_bf16.h>
#include <stdint.h>

// MoE: B=2,S=4096 -> T=8192 tokens, D=1024, E=8, H=2736 (pad->2816), TOPK=2
#define T_TOK 8192
#define DIM   1024
#define NEXP  8
#define HDIM  2736
#define HPAD  2816     // 22 * 128, zero-padded rows/cols are inert
#define CAP   16384    // worst-case tokens per expert
#define HB_ROWS 17408  // 16384 + 8*128 padding, compact h capacity

typedef __attribute__((ext_vector_type(8))) short          short8;   // 8 bf16 (4 VGPRs) MFMA operand
typedef __attribute__((ext_vector_type(8))) unsigned short ushort8;
typedef __attribute__((ext_vector_type(4))) float          f32x4;

__device__ __forceinline__ unsigned short f2bf(float f) {
  unsigned u = __float_as_uint(f);
  u = (u + 0x7FFFu + ((u >> 16) & 1u)) >> 16;   // round-to-nearest-even
  return (unsigned short)u;
}

__device__ __forceinline__ void gld_lds16(const ushort* g, ushort* l) {
  // async global->LDS, 16B/lane; LDS dest must be wave-uniform base (lane*16 added by HW)
  __builtin_amdgcn_global_load_lds((const __attribute__((address_space(1))) uint32_t*)g,
                                   (__attribute__((address_space(3))) uint32_t*)l,
                                   16, 0, 0);
}

// Stage a 128x64 bf16 tile (row stride ldK) into linear LDS [128][64].
__device__ __forceinline__ void stage64(const ushort* __restrict__ src, int ldK,
                                        ushort* lds, int tid) {
#pragma unroll
  for (int i = 0; i < 4; ++i) {
    int c = i * 256 + tid;
    int row = c >> 3, col8 = c & 7;
    gld_lds16(src + (size_t)row * ldK + col8 * 8,
              lds + (size_t)(i * 256 + (tid & 192)) * 8);  // wave-uniform base chunk
  }
}

// ---------------- conversion kernels ----------------
__global__ void cvt_x_kernel(const float* __restrict__ in, ushort* __restrict__ out, int n8) {
  int i = blockIdx.x * 256 + threadIdx.x;
  if (i >= n8) return;
  const float4* p = (const float4*)in + (size_t)i * 2;
  float4 a = p[0], b = p[1];
  ushort8 v;
  v[0]=f2bf(a.x); v[1]=f2bf(a.y); v[2]=f2bf(a.z); v[3]=f2bf(a.w);
  v[4]=f2bf(b.x); v[5]=f2bf(b.y); v[6]=f2bf(b.z); v[7]=f2bf(b.w);
  ((ushort8*)out)[i] = v;
}

// in [E,H,D] fp32 -> out [E,Hp,D] bf16, rows >= H zeroed. D=1024 (D/8=128 pow2).
__global__ void cvt_pad_rows_kernel(const float* __restrict__ in, ushort* __restrict__ out, int n8) {
  int i = blockIdx.x * 256 + threadIdx.x;
  if (i >= n8) return;
  int col = i & 127;          // D/8 = 128
  int rowAll = i >> 7;        // [0, E*Hp)
  int e = rowAll / HPAD;
  int r = rowAll - e * HPAD;
  ushort8 v = (ushort8)0;
  if (r < HDIM) {
    const float4* p = (const float4*)(in + ((size_t)(e * HDIM + r) * DIM + col * 8));
    float4 a = p[0], b = p[1];
    v[0]=f2bf(a.x); v[1]=f2bf(a.y); v[2]=f2bf(a.z); v[3]=f2bf(a.w);
    v[4]=f2bf(b.x); v[5]=f2bf(b.y); v[6]=f2bf(b.z); v[7]=f2bf(b.w);
  }
  ((ushort8*)out)[i] = v;
}

// in [E,D,H] fp32 -> out [E,D,Hp] bf16, inner cols >= H zeroed.
__global__ void cvt_pad_inner_kernel(const float* __restrict__ in, ushort* __restrict__ out, int n8) {
  int i = blockIdx.x * 256 + threadIdx.x;
  if (i >= n8) return;
  int h8 = HPAD / 8;          // 352
  int c = i % h8;
  int rowAll = i / h8;        // [0, E*D)
  int h0 = c * 8;
  ushort8 v = (ushort8)0;
  if (h0 < HDIM) {
    const float4* p = (const float4*)(in + (size_t)rowAll * HDIM + h0);
    float4 a = p[0], b = p[1];
    v[0]=f2bf(a.x); v[1]=f2bf(a.y); v[2]=f2bf(a.z); v[3]=f2bf(a.w);
    v[4]=f2bf(b.x); v[5]=f2bf(b.y); v[6]=f2bf(b.z); v[7]=f2bf(b.w);
  }
  ((ushort8*)out)[i] = v;
}

// ---------------- topk: one wave per token, NO atomics ----------------
__global__ void topk_kernel(const float* __restrict__ X, const float* __restrict__ GW,
                            int* __restrict__ sel0, int* __restrict__ sel1,
                            float* __restrict__ w0, float* __restrict__ w1) {
  int wave = threadIdx.x >> 6, lane = threadIdx.x & 63;
  int t = blockIdx.x * 4 + wave;
  if (t >= T_TOK) return;
  float acc[NEXP];
#pragma unroll
  for (int e = 0; e < NEXP; ++e) acc[e] = 0.f;
  const float4* xv = (const float4*)(X + (size_t)t * DIM);
#pragma unroll
  for (int it = 0; it < DIM / 4 / 64; ++it) {
    int c = it * 64 + lane;
    float4 xx = xv[c];
#pragma unroll
    for (int e = 0; e < NEXP; ++e) {
      float4 w = ((const float4*)(GW + (size_t)e * DIM))[c];
      acc[e] += xx.x * w.x + xx.y * w.y + xx.z * w.z + xx.w * w.w;
    }
  }
#pragma unroll
  for (int e = 0; e < NEXP; ++e)
#pragma unroll
    for (int off = 32; off > 0; off >>= 1)
      acc[e] += __shfl_down(acc[e], off, 64);
  if (lane == 0) {
    float m = acc[0];
#pragma unroll
    for (int e = 1; e < NEXP; ++e) m = fmaxf(m, acc[e]);
    float p[NEXP], s = 0.f;
#pragma unroll
    for (int e = 0; e < NEXP; ++e) { p[e] = expf(acc[e] - m); s += p[e]; }
#pragma unroll
    for (int e = 0; e < NEXP; ++e) p[e] /= s;
    int i0 = 0;
#pragma unroll
    for (int e = 1; e < NEXP; ++e) if (p[e] > p[i0]) i0 = e;   // ties -> lowest idx, matches top_k
    int i1 = (i0 == 0) ? 1 : 0;
#pragma unroll
    for (int e = 0; e < NEXP; ++e) if (e != i0 && p[e] > p[i1]) i1 = e;
    float denom = p[i0] + p[i1] + 1e-8f;
    sel0[t] = i0; sel1[t] = i1;
    w0[t] = p[i0] / denom;
    w1[t] = p[i1] / denom;
  }
}

// ---------------- build per-expert token lists: 1 block/expert, ballot scan, no atomics ----------------
__global__ __launch_bounds__(1024) void build_lists_kernel(
    const int* __restrict__ sel0, const int* __restrict__ sel1,
    int* __restrict__ tok, int* __restrict__ rnk0, int* __restrict__ rnk1,
    int* __restrict__ cnt) {
  int e = blockIdx.x;
  int tid = threadIdx.x;
  int lane = tid & 63, wv = tid >> 6;   // 16 waves
  __shared__ int wsum[16], wbase[16], chunktot;
  int base = 0;
  for (int t0 = 0; t0 < T_TOK; t0 += 1024) {
    int t = t0 + tid;
    int s0 = sel0[t], s1 = sel1[t];
    bool isf = (s0 == e);
    bool hit = isf || (s1 == e);
    unsigned long long b = __ballot(hit);
    int rank = __popcll(b & ((1ULL << lane) - 1ULL));
    if (lane == 0) wsum[wv] = __popcll(b);
    __syncthreads();
    if (tid == 0) {
      int s = 0;
#pragma unroll
      for (int w = 0; w < 16; ++w) { wbase[w] = s; s += wsum[w]; }
      chunktot = s;
    }
    __syncthreads();
    if (hit) {
      int pos = base + wbase[wv] + rank;
      tok[e * CAP + pos] = t;
      if (isf) rnk0[t] = pos; else rnk1[t] = pos;
    }
    base += chunktot;
    __syncthreads();   // protect wsum/wbase/chunktot before next chunk overwrites
  }
  if (tid == 0) cnt[e] = base;
}

// 128-aligned segment offsets for compact h / yc
__global__ void offsets_kernel(const int* __restrict__ cnt, int* __restrict__ off) {
  if (threadIdx.x == 0 && blockIdx.x == 0) {
    int o = 0;
#pragma unroll
    for (int e = 0; e < NEXP; ++e) { off[e] = o; o += (cnt[e] + 127) & ~127; }
    off[NEXP] = o;
  }
}

// ---------------- GEMM1 fused sparse: exact grid + single-barrier dbuf pipeline, BK=32 ----------------
// Block x covers global padded rows [x*128, x*128+128) which lie in exactly one
// expert segment (off[] is 128-aligned). No dead blocks.
__global__ __launch_bounds__(256) void gemm1_all_kernel(
    const ushort* __restrict__ X,     // [T, D] bf16
    const ushort* __restrict__ Wgb,   // [E, HPAD, D]
    const ushort* __restrict__ Wub,   // [E, HPAD, D]
    ushort* __restrict__ Hout,        // [HB_ROWS, HPAD] compact
    const int* __restrict__ tokall,   // [E, CAP]
    const int* __restrict__ cntv, const int* __restrict__ offv) {
  int row0 = blockIdx.x * 128;
  if (row0 >= offv[NEXP]) return;
  int e = 0;
#pragma unroll
  for (int k = 1; k < NEXP; ++k) if (row0 >= offv[k]) e = k;
  int local = row0 - offv[e];
  int cnt = cntv[e];
  const int* tokl = tokall + (size_t)e * CAP;

  __shared__ ushort As[2][128 * 32];   // 8KB per buffer
  __shared__ ushort Bg[2][128 * 32];
  __shared__ ushort Bu[2][128 * 32];
  int tid = threadIdx.x;
  int lane = tid & 63, wave = tid >> 6;
  int wr = wave >> 1, wc = wave & 1;
  int lhi = lane >> 4, llo = lane & 15;
  int bcol = blockIdx.y * 128;
  int ldsoff = tid & 192;              // wave-uniform chunk base

  // A gather pointers: chunk c = i*256+tid -> row = i*64 + (tid>>2), col8 = tid&3
  const ushort* asrc[2];
#pragma unroll
  for (int i = 0; i < 2; ++i) {
    int p = local + (tid >> 2) + 64 * i;
    int t = (p < cnt) ? tokl[p] : 0;   // padded rows: read token 0, result discarded
    asrc[i] = X + (size_t)t * DIM + (tid & 3) * 8;
  }
  const ushort* Bgb2 = Wgb + (size_t)e * HPAD * DIM + (size_t)bcol * DIM;
  const ushort* Bub2 = Wub + (size_t)e * HPAD * DIM + (size_t)bcol * DIM;
  int brow_b = tid >> 2, bcol8 = tid & 3;   // B chunk mapping (i adds 64 rows)

  f32x4 accg[4][4], accu[4][4];
#pragma unroll
  for (int m = 0; m < 4; ++m)
#pragma unroll
    for (int n = 0; n < 4; ++n) { accg[m][n] = (f32x4){0,0,0,0}; accu[m][n] = (f32x4){0,0,0,0}; }

  // prologue: stage K-slice 0 into buffer 0
#pragma unroll
  for (int i = 0; i < 2; ++i) {
    int r = brow_b + 64 * i;
    gld_lds16(asrc[i], &As[0][(size_t)(i * 256 + ldsoff) * 8]);
    gld_lds16(Bgb2 + (size_t)r * DIM + bcol8 * 8, &Bg[0][(size_t)(i * 256 + ldsoff) * 8]);
    gld_lds16(Bub2 + (size_t)r * DIM + bcol8 * 8, &Bu[0][(size_t)(i * 256 + ldsoff) * 8]);
  }
  __syncthreads();

  int buf = 0;
  for (int kidx = 0; kidx < DIM / 32; ++kidx) {
    int ko = (kidx + 1) * 32;
    if (ko < DIM) {                      // stage next slice into other buffer (overlaps compute)
      int nb = buf ^ 1;
#pragma unroll
      for (int i = 0; i < 2; ++i) {
        int r = brow_b + 64 * i;
        gld_lds16(asrc[i] + ko, &As[nb][(size_t)(i * 256 + ldsoff) * 8]);
        gld_lds16(Bgb2 + (size_t)r * DIM + ko + bcol8 * 8, &Bg[nb][(size_t)(i * 256 + ldsoff) * 8]);
        gld_lds16(Bub2 + (size_t)r * DIM + ko + bcol8 * 8, &Bu[nb][(size_t)(i * 256 + ldsoff) * 8]);
      }
    }
    const short8* As8 = (const short8*)As[buf];
    const short8* Bg8 = (const short8*)Bg[buf];
    const short8* Bu8 = (const short8*)Bu[buf];
    short8 a[4], bg[4], bu[4];
#pragma unroll
    for (int m = 0; m < 4; ++m)
      a[m] = As8[(wr * 64 + m * 16 + llo) * 4 + lhi];
#pragma unroll
    for (int n = 0; n < 4; ++n) {
      bg[n] = Bg8[(wc * 64 + n * 16 + llo) * 4 + lhi];
      bu[n] = Bu8[(wc * 64 + n * 16 + llo) * 4 + lhi];
    }
#pragma unroll
    for (int m = 0; m < 4; ++m)
#pragma unroll
      for (int n = 0; n < 4; ++n) {
        accg[m][n] = __builtin_amdgcn_mfma_f32_16x16x32_bf16(a[m], bg[n], accg[m][n], 0, 0, 0);
        accu[m][n] = __builtin_amdgcn_mfma_f32_16x16x32_bf16(a[m], bu[n], accu[m][n], 0, 0, 0);
      }
    __syncthreads();   // drains this wave's gld_lds (vmcnt 0) + all waves done reading buf
    buf ^= 1;
  }
  // epilogue: silu(g)*u -> bf16 into compact h.  C/D layout: col=lane&15, row=(lane>>4)*4+j  [m89]
#pragma unroll
  for (int m = 0; m < 4; ++m)
#pragma unroll
    for (int n = 0; n < 4; ++n)
#pragma unroll
      for (int j = 0; j < 4; ++j) {
        int row = row0 + wr * 64 + m * 16 + lhi * 4 + j;
        int col = bcol + wc * 64 + n * 16 + llo;
        float g = accg[m][n][j];
        float u = accu[m][n][j];
        float h = g / (1.f + __expf(-g)) * u;
        Hout[(size_t)row * HPAD + col] = f2bf(h);
      }
}

// ---------------- GEMM2: exact grid + single-barrier dbuf pipeline, BK=64 ----------------
__global__ __launch_bounds__(256) void gemm2_all_kernel(
    const ushort* __restrict__ Hin,   // [HB_ROWS, HPAD] compact
    const ushort* __restrict__ W2b,   // [E, DIM, HPAD]
    float* __restrict__ Yc,           // [HB_ROWS, DIM] fp32 compact
    const int* __restrict__ offv) {
  int row0 = blockIdx.x * 128;
  if (row0 >= offv[NEXP]) return;
  int e = 0;
#pragma unroll
  for (int k = 1; k < NEXP; ++k) if (row0 >= offv[k]) e = k;

  __shared__ ushort As[2][128 * 64];   // 16KB per buffer
  __shared__ ushort Bs[2][128 * 64];
  int tid = threadIdx.x;
  int lane = tid & 63, wave = tid >> 6;
  int wr = wave >> 1, wc = wave & 1;
  int lhi = lane >> 4, llo = lane & 15;
  int bcol = blockIdx.y * 128;

  f32x4 acc[4][4];
#pragma unroll
  for (int m = 0; m < 4; ++m)
#pragma unroll
    for (int n = 0; n < 4; ++n) acc[m][n] = (f32x4){0,0,0,0};

  const ushort* Ab = Hin + (size_t)row0 * HPAD;
  const ushort* Bb = W2b + (size_t)e * DIM * HPAD + (size_t)bcol * HPAD;

  stage64(Ab, HPAD, As[0], tid);
  stage64(Bb, HPAD, Bs[0], tid);
  __syncthreads();

  int buf = 0;
  for (int kidx = 0; kidx < HPAD / 64; ++kidx) {
    int ko = (kidx + 1) * 64;
    if (ko < HPAD) {
      int nb = buf ^ 1;
      stage64(Ab + ko, HPAD, As[nb], tid);
      stage64(Bb + ko, HPAD, Bs[nb], tid);
    }
    const short8* As8 = (const short8*)As[buf];
    const short8* Bs8 = (const short8*)Bs[buf];
#pragma unroll
    for (int kk = 0; kk < 2; ++kk) {
      short8 a[4], b[4];
#pragma unroll
      for (int m = 0; m < 4; ++m)
        a[m] = As8[(wr * 64 + m * 16 + llo) * 8 + kk * 4 + lhi];
#pragma unroll
      for (int n = 0; n < 4; ++n)
        b[n] = Bs8[(wc * 64 + n * 16 + llo) * 8 + kk * 4 + lhi];
#pragma unroll
      for (int m = 0; m < 4; ++m)
#pragma unroll
        for (int n = 0; n < 4; ++n)
          acc[m][n] = __builtin_amdgcn_mfma_f32_16x16x32_bf16(a[m], b[n], acc[m][n], 0, 0, 0);
    }
    __syncthreads();
    buf ^= 1;
  }
  // write all 128 rows (incl. segment pad rows; combine never reads pad rows)
#pragma unroll
  for (int m = 0; m < 4; ++m)
#pragma unroll
    for (int j = 0; j < 4; ++j) {
      int row = row0 + wr * 64 + m * 16 + lhi * 4 + j;
#pragma unroll
      for (int n = 0; n < 4; ++n) {
        int col = bcol + wc * 64 + n * 16 + llo;
        Yc[(size_t)row * DIM + col] = acc[m][n][j];
      }
    }
}

// ---------------- combine: out[t] = w0*yc[r0] + w1*yc[r1]; 1 block per token ----------------
__global__ __launch_bounds__(256) void combine_kernel(
    const float* __restrict__ Yc,
    const int* __restrict__ sel0, const int* __restrict__ sel1,
    const float* __restrict__ w0, const float* __restrict__ w1,
    const int* __restrict__ rnk0, const int* __restrict__ rnk1,
    const int* __restrict__ offv, float* __restrict__ out) {
  int t = blockIdx.x;
  int c = threadIdx.x;           // DIM/4 = 256 float4 per row
  int r0 = offv[sel0[t]] + rnk0[t];
  int r1 = offv[sel1[t]] + rnk1[t];
  float a = w0[t], b = w1[t];
  float4 y0 = ((const float4*)(Yc + (size_t)r0 * DIM))[c];
  float4 y1 = ((const float4*)(Yc + (size_t)r1 * DIM))[c];
  float4 o;
  o.x = a * y0.x + b * y1.x;
  o.y = a * y0.y + b * y1.y;
  o.z = a * y0.z + b * y1.z;
  o.w = a * y0.w + b * y1.w;
  ((float4*)(out + (size_t)t * DIM))[c] = o;
}

extern "C" void kernel_launch(void* const* d_in, const int* in_sizes, int n_in,
                              void* d_out, int out_size, void* d_ws, size_t ws_size,
                              hipStream_t stream) {
  const float* x  = (const float*)d_in[0];   // [T, D]
  const float* gw = (const float*)d_in[1];   // [E, D]
  const float* Wg = (const float*)d_in[2];   // [E, H, D]
  const float* W1 = (const float*)d_in[3];   // [E, H, D]
  const float* W2 = (const float*)d_in[4];   // [E, D, H]
  float* out = (float*)d_out;                // [T, D] fp32

  // workspace layout (~255 MB). yc (71.3 MB fp32) aliases Wgb+W1b (92.3 MB),
  // both dead after gemm1_all completes (same-stream ordering).
  char* p = (char*)d_ws;
  ushort* xb  = (ushort*)p; p += (size_t)T_TOK * DIM * 2;
  ushort* Wgb = (ushort*)p; p += (size_t)NEXP * HPAD * DIM * 2;
  ushort* W1b = (ushort*)p; p += (size_t)NEXP * HPAD * DIM * 2;
  ushort* W2b = (ushort*)p; p += (size_t)NEXP * DIM * HPAD * 2;
  ushort* hb  = (ushort*)p; p += (size_t)HB_ROWS * HPAD * 2;
  int*    tok = (int*)p;    p += (size_t)NEXP * CAP * 4;
  int*   sel0 = (int*)p;    p += T_TOK * 4;
  int*   sel1 = (int*)p;    p += T_TOK * 4;
  float*   w0 = (float*)p;  p += T_TOK * 4;
  float*   w1 = (float*)p;  p += T_TOK * 4;
  int*   rnk0 = (int*)p;    p += T_TOK * 4;
  int*   rnk1 = (int*)p;    p += T_TOK * 4;
  int*    cnt = (int*)p;    p += NEXP * 4;
  int*    off = (int*)p;    p += (NEXP + 1) * 4;
  float*  yc  = (float*)Wgb;   // alias

  { int n8 = T_TOK * DIM / 8;
    cvt_x_kernel<<<n8 / 256, 256, 0, stream>>>(x, xb, n8); }
  { int n8 = NEXP * HPAD * DIM / 8;
    cvt_pad_rows_kernel<<<n8 / 256, 256, 0, stream>>>(Wg, Wgb, n8);
    cvt_pad_rows_kernel<<<n8 / 256, 256, 0, stream>>>(W1, W1b, n8);
    cvt_pad_inner_kernel<<<n8 / 256, 256, 0, stream>>>(W2, W2b, n8); }

  topk_kernel<<<T_TOK / 4, 256, 0, stream>>>(x, gw, sel0, sel1, w0, w1);
  build_lists_kernel<<<NEXP, 1024, 0, stream>>>(sel0, sel1, tok, rnk0, rnk1, cnt);
  offsets_kernel<<<1, 64, 0, stream>>>(cnt, off);

  gemm1_all_kernel<<<dim3(HB_ROWS / 128, HPAD / 128), 256, 0, stream>>>(
      xb, Wgb, W1b, hb, tok, cnt, off);
  gemm2_all_kernel<<<dim3(HB_ROWS / 128, DIM / 128), 256, 0, stream>>>(
      hb, W2b, yc, off);
  combine_kernel<<<T_TOK, 256, 0, stream>>>(yc, sel0, sel1, w0, w1, rnk0, rnk1, off, out);
}

// Round 12
// 821.446 us; speedup vs baseline: 3.3176x; 1.1504x over previous
//
#include <hip/hip_runtime.h>
#include <hip/hip_bf16.h>
#include <stdint.h>

// MoE: B=2,S=4096 -> T=8192 tokens, D=1024, E=8, H=2736 (pad->2816), TOPK=2
#define T_TOK 8192
#define DIM   1024
#define NEXP  8
#define HDIM  2736
#define HPAD  2816     // 22 * 128, zero-padded rows/cols are inert
#define CAP   16384    // worst-case tokens per expert
#define HB_ROWS 17408  // 136 * 128, compact h capacity

typedef __attribute__((ext_vector_type(8))) short          short8;   // 8 bf16 (4 VGPRs) MFMA operand
typedef __attribute__((ext_vector_type(8))) unsigned short ushort8;
typedef __attribute__((ext_vector_type(4))) float          f32x4;

__device__ __forceinline__ unsigned short f2bf(float f) {
  unsigned u = __float_as_uint(f);
  u = (u + 0x7FFFu + ((u >> 16) & 1u)) >> 16;   // round-to-nearest-even
  return (unsigned short)u;
}

__device__ __forceinline__ void gld_lds16(const ushort* g, ushort* l) {
  // async global->LDS, 16B/lane; LDS dest must be wave-uniform base (lane*16 added by HW)
  __builtin_amdgcn_global_load_lds((const __attribute__((address_space(1))) uint32_t*)g,
                                   (__attribute__((address_space(3))) uint32_t*)l,
                                   16, 0, 0);
}

// ---------------- conversion kernels ----------------
__global__ void cvt_x_kernel(const float* __restrict__ in, ushort* __restrict__ out, int n8) {
  int i = blockIdx.x * 256 + threadIdx.x;
  if (i >= n8) return;
  const float4* p = (const float4*)in + (size_t)i * 2;
  float4 a = p[0], b = p[1];
  ushort8 v;
  v[0]=f2bf(a.x); v[1]=f2bf(a.y); v[2]=f2bf(a.z); v[3]=f2bf(a.w);
  v[4]=f2bf(b.x); v[5]=f2bf(b.y); v[6]=f2bf(b.z); v[7]=f2bf(b.w);
  ((ushort8*)out)[i] = v;
}

// in [E,H,D] fp32 -> out [E,Hp,D] bf16, rows >= H zeroed. D=1024 (D/8=128 pow2).
__global__ void cvt_pad_rows_kernel(const float* __restrict__ in, ushort* __restrict__ out, int n8) {
  int i = blockIdx.x * 256 + threadIdx.x;
  if (i >= n8) return;
  int col = i & 127;          // D/8 = 128
  int rowAll = i >> 7;        // [0, E*Hp)
  int e = rowAll / HPAD;
  int r = rowAll - e * HPAD;
  ushort8 v = (ushort8)0;
  if (r < HDIM) {
    const float4* p = (const float4*)(in + ((size_t)(e * HDIM + r) * DIM + col * 8));
    float4 a = p[0], b = p[1];
    v[0]=f2bf(a.x); v[1]=f2bf(a.y); v[2]=f2bf(a.z); v[3]=f2bf(a.w);
    v[4]=f2bf(b.x); v[5]=f2bf(b.y); v[6]=f2bf(b.z); v[7]=f2bf(b.w);
  }
  ((ushort8*)out)[i] = v;
}

// in [E,D,H] fp32 -> out [E,D,Hp] bf16, inner cols >= H zeroed.
__global__ void cvt_pad_inner_kernel(const float* __restrict__ in, ushort* __restrict__ out, int n8) {
  int i = blockIdx.x * 256 + threadIdx.x;
  if (i >= n8) return;
  int h8 = HPAD / 8;          // 352
  int c = i % h8;
  int rowAll = i / h8;        // [0, E*D)
  int h0 = c * 8;
  ushort8 v = (ushort8)0;
  if (h0 < HDIM) {
    const float4* p = (const float4*)(in + (size_t)rowAll * HDIM + h0);
    float4 a = p[0], b = p[1];
    v[0]=f2bf(a.x); v[1]=f2bf(a.y); v[2]=f2bf(a.z); v[3]=f2bf(a.w);
    v[4]=f2bf(b.x); v[5]=f2bf(b.y); v[6]=f2bf(b.z); v[7]=f2bf(b.w);
  }
  ((ushort8*)out)[i] = v;
}

// ---------------- topk: one wave per token, NO atomics ----------------
__global__ void topk_kernel(const float* __restrict__ X, const float* __restrict__ GW,
                            int* __restrict__ sel0, int* __restrict__ sel1,
                            float* __restrict__ w0, float* __restrict__ w1) {
  int wave = threadIdx.x >> 6, lane = threadIdx.x & 63;
  int t = blockIdx.x * 4 + wave;
  if (t >= T_TOK) return;
  float acc[NEXP];
#pragma unroll
  for (int e = 0; e < NEXP; ++e) acc[e] = 0.f;
  const float4* xv = (const float4*)(X + (size_t)t * DIM);
#pragma unroll
  for (int it = 0; it < DIM / 4 / 64; ++it) {
    int c = it * 64 + lane;
    float4 xx = xv[c];
#pragma unroll
    for (int e = 0; e < NEXP; ++e) {
      float4 w = ((const float4*)(GW + (size_t)e * DIM))[c];
      acc[e] += xx.x * w.x + xx.y * w.y + xx.z * w.z + xx.w * w.w;
    }
  }
#pragma unroll
  for (int e = 0; e < NEXP; ++e)
#pragma unroll
    for (int off = 32; off > 0; off >>= 1)
      acc[e] += __shfl_down(acc[e], off, 64);
  if (lane == 0) {
    float m = acc[0];
#pragma unroll
    for (int e = 1; e < NEXP; ++e) m = fmaxf(m, acc[e]);
    float p[NEXP], s = 0.f;
#pragma unroll
    for (int e = 0; e < NEXP; ++e) { p[e] = expf(acc[e] - m); s += p[e]; }
#pragma unroll
    for (int e = 0; e < NEXP; ++e) p[e] /= s;
    int i0 = 0;
#pragma unroll
    for (int e = 1; e < NEXP; ++e) if (p[e] > p[i0]) i0 = e;   // ties -> lowest idx, matches top_k
    int i1 = (i0 == 0) ? 1 : 0;
#pragma unroll
    for (int e = 0; e < NEXP; ++e) if (e != i0 && p[e] > p[i1]) i1 = e;
    float denom = p[i0] + p[i1] + 1e-8f;
    sel0[t] = i0; sel1[t] = i1;
    w0[t] = p[i0] / denom;
    w1[t] = p[i1] / denom;
  }
}

// ---------------- build per-expert token lists: 1 block/expert, ballot scan, no atomics ----------------
__global__ __launch_bounds__(1024) void build_lists_kernel(
    const int* __restrict__ sel0, const int* __restrict__ sel1,
    int* __restrict__ tok, int* __restrict__ rnk0, int* __restrict__ rnk1,
    int* __restrict__ cnt) {
  int e = blockIdx.x;
  int tid = threadIdx.x;
  int lane = tid & 63, wv = tid >> 6;   // 16 waves
  __shared__ int wsum[16], wbase[16], chunktot;
  int base = 0;
  for (int t0 = 0; t0 < T_TOK; t0 += 1024) {
    int t = t0 + tid;
    int s0 = sel0[t], s1 = sel1[t];
    bool isf = (s0 == e);
    bool hit = isf || (s1 == e);
    unsigned long long b = __ballot(hit);
    int rank = __popcll(b & ((1ULL << lane) - 1ULL));
    if (lane == 0) wsum[wv] = __popcll(b);
    __syncthreads();
    if (tid == 0) {
      int s = 0;
#pragma unroll
      for (int w = 0; w < 16; ++w) { wbase[w] = s; s += wsum[w]; }
      chunktot = s;
    }
    __syncthreads();
    if (hit) {
      int pos = base + wbase[wv] + rank;
      tok[e * CAP + pos] = t;
      if (isf) rnk0[t] = pos; else rnk1[t] = pos;
    }
    base += chunktot;
    __syncthreads();   // protect wsum/wbase/chunktot before next chunk overwrites
  }
  if (tid == 0) cnt[e] = base;
}

// 128-aligned segment offsets for compact h / yc
__global__ void offsets_kernel(const int* __restrict__ cnt, int* __restrict__ off) {
  if (threadIdx.x == 0 && blockIdx.x == 0) {
    int o = 0;
#pragma unroll
    for (int e = 0; e < NEXP; ++e) { off[e] = o; o += (cnt[e] + 127) & ~127; }
    off[NEXP] = o;
  }
}

// ---------------- GEMM1 fused sparse: 512 thr, XCD swizzle, dbuf BK=32 ----------------
// 8 waves (2x4), wave tile 64x32. Block covers rows [bx*128, +128) = one expert segment.
__global__ __launch_bounds__(512) void gemm1_all_kernel(
    const ushort* __restrict__ X,     // [T, D] bf16
    const ushort* __restrict__ Wgb,   // [E, HPAD, D]
    const ushort* __restrict__ Wub,   // [E, HPAD, D]
    ushort* __restrict__ Hout,        // [HB_ROWS, HPAD] compact
    const int* __restrict__ tokall,   // [E, CAP]
    const int* __restrict__ cntv, const int* __restrict__ offv) {
  // XCD swizzle: NWG = 136*22 = 2992 = 8*374. Same-y x-runs colocate per XCD -> weight L2 hits.
  int d = blockIdx.x + 136 * blockIdx.y;
  int lid = (d & 7) * (2992 / 8) + (d >> 3);
  int bx = lid % 136, by = lid / 136;

  int row0 = bx * 128;
  if (row0 >= offv[NEXP]) return;
  int e = 0;
#pragma unroll
  for (int k = 1; k < NEXP; ++k) if (row0 >= offv[k]) e = k;
  int local = row0 - offv[e];
  int cnt = cntv[e];
  const int* tokl = tokall + (size_t)e * CAP;

  __shared__ ushort As[2][128 * 32];   // 8KB per buffer; total 48KB
  __shared__ ushort Bg[2][128 * 32];
  __shared__ ushort Bu[2][128 * 32];
  int tid = threadIdx.x;
  int lane = tid & 63, wave = tid >> 6;   // 8 waves
  int wr = wave >> 2, wc = wave & 3;      // 2 x 4 wave grid
  int lhi = lane >> 4, llo = lane & 15;
  int bcol = by * 128;
  int ldsoff8 = (tid & 448) * 8;          // wave-uniform chunk base (ushort units)

  // staging: tile 128x32 = 512 chunks of 16B; thread stages chunk tid.
  // chunk c -> row c>>2, col8 c&3.
  int p = local + (tid >> 2);
  int t = (p < cnt) ? tokl[p] : 0;        // padded rows: read token 0, result discarded
  const ushort* asrc = X + (size_t)t * DIM + (tid & 3) * 8;
  const ushort* bgsrc = Wgb + (size_t)e * HPAD * DIM + ((size_t)bcol + (tid >> 2)) * DIM + (tid & 3) * 8;
  const ushort* busrc = Wub + (size_t)e * HPAD * DIM + ((size_t)bcol + (tid >> 2)) * DIM + (tid & 3) * 8;

  f32x4 accg[4][2], accu[4][2];
#pragma unroll
  for (int m = 0; m < 4; ++m)
#pragma unroll
    for (int n = 0; n < 2; ++n) { accg[m][n] = (f32x4){0,0,0,0}; accu[m][n] = (f32x4){0,0,0,0}; }

  // prologue: stage K-slice 0 into buffer 0
  gld_lds16(asrc,  &As[0][ldsoff8]);
  gld_lds16(bgsrc, &Bg[0][ldsoff8]);
  gld_lds16(busrc, &Bu[0][ldsoff8]);
  __syncthreads();

  int buf = 0;
  for (int kidx = 0; kidx < DIM / 32; ++kidx) {
    int ko = (kidx + 1) * 32;
    if (ko < DIM) {                      // stage next slice into other buffer (overlaps compute)
      int nb = buf ^ 1;
      gld_lds16(asrc + ko,  &As[nb][ldsoff8]);
      gld_lds16(bgsrc + ko, &Bg[nb][ldsoff8]);
      gld_lds16(busrc + ko, &Bu[nb][ldsoff8]);
    }
    const short8* As8 = (const short8*)As[buf];
    const short8* Bg8 = (const short8*)Bg[buf];
    const short8* Bu8 = (const short8*)Bu[buf];
    short8 a[4], bg[2], bu[2];
#pragma unroll
    for (int m = 0; m < 4; ++m)
      a[m] = As8[(wr * 64 + m * 16 + llo) * 4 + lhi];
#pragma unroll
    for (int n = 0; n < 2; ++n) {
      bg[n] = Bg8[(wc * 32 + n * 16 + llo) * 4 + lhi];
      bu[n] = Bu8[(wc * 32 + n * 16 + llo) * 4 + lhi];
    }
#pragma unroll
    for (int m = 0; m < 4; ++m)
#pragma unroll
      for (int n = 0; n < 2; ++n) {
        accg[m][n] = __builtin_amdgcn_mfma_f32_16x16x32_bf16(a[m], bg[n], accg[m][n], 0, 0, 0);
        accu[m][n] = __builtin_amdgcn_mfma_f32_16x16x32_bf16(a[m], bu[n], accu[m][n], 0, 0, 0);
      }
    __syncthreads();   // drains this step's gld_lds + all waves done reading buf
    buf ^= 1;
  }
  // epilogue: silu(g)*u -> bf16.  C/D layout: col=lane&15, row=(lane>>4)*4+j  [m89]
#pragma unroll
  for (int m = 0; m < 4; ++m)
#pragma unroll
    for (int n = 0; n < 2; ++n)
#pragma unroll
      for (int j = 0; j < 4; ++j) {
        int row = row0 + wr * 64 + m * 16 + lhi * 4 + j;
        int col = bcol + wc * 32 + n * 16 + llo;
        float g = accg[m][n][j];
        float u = accu[m][n][j];
        float h = g / (1.f + __expf(-g)) * u;
        Hout[(size_t)row * HPAD + col] = f2bf(h);
      }
}

// ---------------- GEMM2: 512 thr, XCD swizzle, dbuf BK=64 ----------------
__global__ __launch_bounds__(512) void gemm2_all_kernel(
    const ushort* __restrict__ Hin,   // [HB_ROWS, HPAD] compact
    const ushort* __restrict__ W2b,   // [E, DIM, HPAD]
    float* __restrict__ Yc,           // [HB_ROWS, DIM] fp32 compact
    const int* __restrict__ offv) {
  // XCD swizzle: NWG = 136*8 = 1088 = 8*136 -> each XCD owns one full y-column.
  int d = blockIdx.x + 136 * blockIdx.y;
  int lid = (d & 7) * (1088 / 8) + (d >> 3);
  int bx = lid % 136, by = lid / 136;

  int row0 = bx * 128;
  if (row0 >= offv[NEXP]) return;
  int e = 0;
#pragma unroll
  for (int k = 1; k < NEXP; ++k) if (row0 >= offv[k]) e = k;

  __shared__ ushort As[2][128 * 64];   // 16KB per buffer; total 64KB
  __shared__ ushort Bs[2][128 * 64];
  int tid = threadIdx.x;
  int lane = tid & 63, wave = tid >> 6;   // 8 waves
  int wr = wave >> 2, wc = wave & 3;      // 2 x 4
  int lhi = lane >> 4, llo = lane & 15;
  int bcol = by * 128;
  int ldsoff8 = (tid & 448) * 8;

  f32x4 acc[4][2];
#pragma unroll
  for (int m = 0; m < 4; ++m)
#pragma unroll
    for (int n = 0; n < 2; ++n) acc[m][n] = (f32x4){0,0,0,0};

  // tile 128x64 = 1024 chunks; thread stages chunks tid and tid+512.
  // chunk c -> row c>>3, col8 c&7.
  const ushort* Ab = Hin + (size_t)row0 * HPAD + (size_t)(tid >> 3) * HPAD + (tid & 7) * 8;
  const ushort* Bb = W2b + (size_t)e * DIM * HPAD + ((size_t)bcol + (tid >> 3)) * HPAD + (tid & 7) * 8;

  // prologue
#pragma unroll
  for (int i = 0; i < 2; ++i) {
    gld_lds16(Ab + (size_t)i * 64 * HPAD, &As[0][(size_t)i * 512 * 8 + ldsoff8]);
    gld_lds16(Bb + (size_t)i * 64 * HPAD, &Bs[0][(size_t)i * 512 * 8 + ldsoff8]);
  }
  __syncthreads();

  int buf = 0;
  for (int kidx = 0; kidx < HPAD / 64; ++kidx) {
    int ko = (kidx + 1) * 64;
    if (ko < HPAD) {
      int nb = buf ^ 1;
#pragma unroll
      for (int i = 0; i < 2; ++i) {
        gld_lds16(Ab + (size_t)i * 64 * HPAD + ko, &As[nb][(size_t)i * 512 * 8 + ldsoff8]);
        gld_lds16(Bb + (size_t)i * 64 * HPAD + ko, &Bs[nb][(size_t)i * 512 * 8 + ldsoff8]);
      }
    }
    const short8* As8 = (const short8*)As[buf];
    const short8* Bs8 = (const short8*)Bs[buf];
#pragma unroll
    for (int kk = 0; kk < 2; ++kk) {
      short8 a[4], b[2];
#pragma unroll
      for (int m = 0; m < 4; ++m)
        a[m] = As8[(wr * 64 + m * 16 + llo) * 8 + kk * 4 + lhi];
#pragma unroll
      for (int n = 0; n < 2; ++n)
        b[n] = Bs8[(wc * 32 + n * 16 + llo) * 8 + kk * 4 + lhi];
#pragma unroll
      for (int m = 0; m < 4; ++m)
#pragma unroll
        for (int n = 0; n < 2; ++n)
          acc[m][n] = __builtin_amdgcn_mfma_f32_16x16x32_bf16(a[m], b[n], acc[m][n], 0, 0, 0);
    }
    __syncthreads();
    buf ^= 1;
  }
  // write all 128 rows (incl. segment pad rows; combine never reads pad rows)
#pragma unroll
  for (int m = 0; m < 4; ++m)
#pragma unroll
    for (int j = 0; j < 4; ++j) {
      int row = row0 + wr * 64 + m * 16 + lhi * 4 + j;
#pragma unroll
      for (int n = 0; n < 2; ++n) {
        int col = bcol + wc * 32 + n * 16 + llo;
        Yc[(size_t)row * DIM + col] = acc[m][n][j];
      }
    }
}

// ---------------- combine: out[t] = w0*yc[r0] + w1*yc[r1]; 1 block per token ----------------
__global__ __launch_bounds__(256) void combine_kernel(
    const float* __restrict__ Yc,
    const int* __restrict__ sel0, const int* __restrict__ sel1,
    const float* __restrict__ w0, const float* __restrict__ w1,
    const int* __restrict__ rnk0, const int* __restrict__ rnk1,
    const int* __restrict__ offv, float* __restrict__ out) {
  int t = blockIdx.x;
  int c = threadIdx.x;           // DIM/4 = 256 float4 per row
  int r0 = offv[sel0[t]] + rnk0[t];
  int r1 = offv[sel1[t]] + rnk1[t];
  float a = w0[t], b = w1[t];
  float4 y0 = ((const float4*)(Yc + (size_t)r0 * DIM))[c];
  float4 y1 = ((const float4*)(Yc + (size_t)r1 * DIM))[c];
  float4 o;
  o.x = a * y0.x + b * y1.x;
  o.y = a * y0.y + b * y1.y;
  o.z = a * y0.z + b * y1.z;
  o.w = a * y0.w + b * y1.w;
  ((float4*)(out + (size_t)t * DIM))[c] = o;
}

extern "C" void kernel_launch(void* const* d_in, const int* in_sizes, int n_in,
                              void* d_out, int out_size, void* d_ws, size_t ws_size,
                              hipStream_t stream) {
  const float* x  = (const float*)d_in[0];   // [T, D]
  const float* gw = (const float*)d_in[1];   // [E, D]
  const float* Wg = (const float*)d_in[2];   // [E, H, D]
  const float* W1 = (const float*)d_in[3];   // [E, H, D]
  const float* W2 = (const float*)d_in[4];   // [E, D, H]
  float* out = (float*)d_out;                // [T, D] fp32

  // workspace layout (~255 MB). yc (71.3 MB fp32) aliases Wgb+W1b (92.3 MB),
  // both dead after gemm1_all completes (same-stream ordering).
  char* p = (char*)d_ws;
  ushort* xb  = (ushort*)p; p += (size_t)T_TOK * DIM * 2;
  ushort* Wgb = (ushort*)p; p += (size_t)NEXP * HPAD * DIM * 2;
  ushort* W1b = (ushort*)p; p += (size_t)NEXP * HPAD * DIM * 2;
  ushort* W2b = (ushort*)p; p += (size_t)NEXP * DIM * HPAD * 2;
  ushort* hb  = (ushort*)p; p += (size_t)HB_ROWS * HPAD * 2;
  int*    tok = (int*)p;    p += (size_t)NEXP * CAP * 4;
  int*   sel0 = (int*)p;    p += T_TOK * 4;
  int*   sel1 = (int*)p;    p += T_TOK * 4;
  float*   w0 = (float*)p;  p += T_TOK * 4;
  float*   w1 = (float*)p;  p += T_TOK * 4;
  int*   rnk0 = (int*)p;    p += T_TOK * 4;
  int*   rnk1 = (int*)p;    p += T_TOK * 4;
  int*    cnt = (int*)p;    p += NEXP * 4;
  int*    off = (int*)p;    p += (NEXP + 1) * 4;
  float*  yc  = (float*)Wgb;   // alias

  { int n8 = T_TOK * DIM / 8;
    cvt_x_kernel<<<n8 / 256, 256, 0, stream>>>(x, xb, n8); }
  { int n8 = NEXP * HPAD * DIM / 8;
    cvt_pad_rows_kernel<<<n8 / 256, 256, 0, stream>>>(Wg, Wgb, n8);
    cvt_pad_rows_kernel<<<n8 / 256, 256, 0, stream>>>(W1, W1b, n8);
    cvt_pad_inner_kernel<<<n8 / 256, 256, 0, stream>>>(W2, W2b, n8); }

  topk_kernel<<<T_TOK / 4, 256, 0, stream>>>(x, gw, sel0, sel1, w0, w1);
  build_lists_kernel<<<NEXP, 1024, 0, stream>>>(sel0, sel1, tok, rnk0, rnk1, cnt);
  offsets_kernel<<<1, 64, 0, stream>>>(cnt, off);

  gemm1_all_kernel<<<dim3(HB_ROWS / 128, HPAD / 128), 512, 0, stream>>>(
      xb, Wgb, W1b, hb, tok, cnt, off);
  gemm2_all_kernel<<<dim3(HB_ROWS / 128, DIM / 128), 512, 0, stream>>>(
      hb, W2b, yc, off);
  combine_kernel<<<T_TOK, 256, 0, stream>>>(yc, sel0, sel1, w0, w1, rnk0, rnk1, off, out);
}